// Round 7
// baseline (90.716 us; speedup 1.0000x reference)
//
#include <hip/hip_runtime.h>
#include <math.h>

// GyroLoss: fused so3_exp / bmtm / so3_log / Huber-mean over (64, 8192) rows.
// R7: R6 crashed — float4 at row*36 B is only 4B-aligned (dwordx4 fault).
// Fix: 4 consecutive rows per thread -> chunk = 144 B xs (16*9) / 240 B hx
// (16*15), so ALL float4 loads are naturally 16B-aligned. No LDS, no
// barriers, 24 independent loads issued up front (single vmcnt drain), then
// 4 fully-unrolled row computations on statically-indexed registers.

namespace {
constexpr int kN = 64;
constexpr int kT = 8192;
constexpr int kN0 = 5;
constexpr int kRows = kN * kT;                  // 524288
constexpr int kRowsPerThread = 4;
constexpr int kThreadsPerBlock = 256;
constexpr int kRowsPerBlock = kThreadsPerBlock * kRowsPerThread;  // 1024
constexpr int kBlocks = kRows / kRowsPerBlock;  // 512
constexpr int kWavesPerBlock = kThreadsPerBlock / 64;  // 4
constexpr int kPartials = kBlocks * kWavesPerBlock;    // 2048
// out = W * HUBER^2 * mean = 25 * sum / (64 * 8187 * 15)
constexpr float kScale = (float)(25.0 / ((double)kN * (double)(kT - kN0) * 15.0));
}

// Abramowitz-Stegun 4.4.45: acos(x) ~ sqrt(1-|x|)*poly(|x|). Abs err ~1e-4 rad.
__device__ __forceinline__ float fast_acos(float x) {
    float xa = fabsf(x);
    float p = fmaf(xa, fmaf(xa, fmaf(xa, -0.0187293f, 0.0742610f), -0.2121144f), 1.5707288f);
    float r = sqrtf(fmaxf(1.0f - xa, 0.0f)) * p;
    return x < 0.0f ? 3.14159265f - r : r;
}

// Rodrigues: R = I + A*K + B*K^2. 1/theta via rsqrt — no divides, no sqrt.
__device__ __forceinline__ void so3_exp9(float x, float y, float z, float R[9]) {
    float t2 = x * x + y * y + z * z;
    bool sm = t2 < 1e-8f;
    float st2 = sm ? 1.0f : t2;
    float rth = rsqrtf(st2);       // 1/theta
    float th = st2 * rth;          // theta
    float s, c;
    __sincosf(th, &s, &c);
    float A = sm ? (1.0f - t2 * (1.0f / 6.0f)) : (s * rth);
    float B = sm ? (0.5f - t2 * (1.0f / 24.0f)) : ((1.0f - c) * rth * rth);
    R[0] = 1.0f - B * (y * y + z * z);
    R[1] = B * x * y - A * z;
    R[2] = B * x * z + A * y;
    R[3] = B * x * y + A * z;
    R[4] = 1.0f - B * (x * x + z * z);
    R[5] = B * y * z - A * x;
    R[6] = B * x * z - A * y;
    R[7] = B * y * z + A * x;
    R[8] = 1.0f - B * (x * x + y * y);
}

// out = so3_log(a^T * b); C[i][k] = sum_j a[3j+i] * b[3j+k]
__device__ __forceinline__ void bmtm_log(const float a[9], const float b[9], float out[3]) {
    float C00 = a[0] * b[0] + a[3] * b[3] + a[6] * b[6];
    float C11 = a[1] * b[1] + a[4] * b[4] + a[7] * b[7];
    float C22 = a[2] * b[2] + a[5] * b[5] + a[8] * b[8];
    float C21 = a[2] * b[1] + a[5] * b[4] + a[8] * b[7];
    float C12 = a[1] * b[2] + a[4] * b[5] + a[7] * b[8];
    float C02 = a[0] * b[2] + a[3] * b[5] + a[6] * b[8];
    float C20 = a[2] * b[0] + a[5] * b[3] + a[8] * b[6];
    float C10 = a[1] * b[0] + a[4] * b[3] + a[7] * b[6];
    float C01 = a[0] * b[1] + a[3] * b[4] + a[6] * b[7];
    float tr = C00 + C11 + C22;
    float cs = 0.5f * (tr - 1.0f);
    cs = fminf(1.0f, fmaxf(-1.0f, cs));
    bool sm = cs > (1.0f - 1e-6f);
    float ang = fast_acos(sm ? 0.0f : cs);
    // sin(acos(c)) == sqrt(1-c^2)
    float factor = sm ? 0.5f : 0.5f * ang * rsqrtf(fmaxf(1.0f - cs * cs, 1e-30f));
    out[0] = factor * (C21 - C12);
    out[1] = factor * (C02 - C20);
    out[2] = factor * (C10 - C01);
}

__device__ __forceinline__ float huber_term(float r) {
    float z = r * 200.0f;  // 1/HUBER
    float az = fabsf(z);
    return az < 1.0f ? 0.5f * z * z : az - 0.5f;
}

__global__ __launch_bounds__(256) void gyro_loss_kernel(
    const float* __restrict__ xs, const float* __restrict__ hx,
    float* __restrict__ partials) {
    const int tid = threadIdx.x;
    const long chunk = (long)blockIdx.x * kThreadsPerBlock + tid;  // 4-row chunk id
    const long row0 = chunk * kRowsPerThread;

    // 16B-aligned float4 loads: chunk bases are 144B (xs) / 240B (hx) multiples.
    const float4* xp = reinterpret_cast<const float4*>(xs + row0 * 9);   // 9 float4
    const float4* hp = reinterpret_cast<const float4*>(hx + row0 * 15);  // 15 float4
    float a[36], h[60];
#pragma unroll
    for (int i = 0; i < 9; ++i) {
        float4 v = xp[i];
        a[4 * i] = v.x; a[4 * i + 1] = v.y; a[4 * i + 2] = v.z; a[4 * i + 3] = v.w;
    }
#pragma unroll
    for (int i = 0; i < 15; ++i) {
        float4 v = hp[i];
        h[4 * i] = v.x; h[4 * i + 1] = v.y; h[4 * i + 2] = v.z; h[4 * i + 3] = v.w;
    }

    float sum = 0.0f;
    const int t0 = (int)(row0 & (kT - 1));  // row0..row0+3 never cross a T-boundary? they can:
    // rows are consecutive; T=8192 is a multiple of 4, and row0 % 4 == 0, so
    // the 4-row chunk never straddles a sequence boundary; t for row j = t0 + j.
#pragma unroll
    for (int j = 0; j < kRowsPerThread; ++j) {
        if (t0 + j < kN0) continue;  // uniform across wave except 2 chunks/grid
        const float* x = a + 9 * j;
        const float* hh = h + 15 * j;
        float Rw[9], Ro[9], Rx[9];
        so3_exp9(x[0], x[1], x[2], Rw);     // omegas
        so3_exp9(hh[0], hh[1], hh[2], Ro);  // hat_omegas
        so3_exp9(hh[6], hh[7], hh[8], Rx);  // hat_xi
        float l1[3], l3[3];
        bmtm_log(Rw, Ro, l1);
        bmtm_log(Rw, Rx, l3);
        sum += huber_term(6.0f * l1[0]) + huber_term(6.0f * l1[1]) + huber_term(6.0f * l1[2]);
        sum += huber_term(6.0f * (x[3] - hh[3])) + huber_term(6.0f * (x[4] - hh[4])) +
               huber_term(6.0f * (x[5] - hh[5]));
        sum += huber_term(l3[0]) + huber_term(l3[1]) + huber_term(l3[2]);
        sum += huber_term(x[3] - hh[9]) + huber_term(x[4] - hh[10]) + huber_term(x[5] - hh[11]);
        sum += huber_term(x[6] - hh[12]) + huber_term(x[7] - hh[13]) + huber_term(x[8] - hh[14]);
    }

    // wave64 butterfly reduce; one plain store per wave. No barriers anywhere.
#pragma unroll
    for (int off = 32; off > 0; off >>= 1) sum += __shfl_down(sum, off, 64);
    if ((tid & 63) == 0) partials[blockIdx.x * kWavesPerBlock + (tid >> 6)] = sum;
}

__global__ __launch_bounds__(256) void reduce_kernel(const float* __restrict__ partials,
                                                     float* __restrict__ out) {
    const int tid = threadIdx.x;
    const float4* p4 = reinterpret_cast<const float4*>(partials);
    float sum = 0.0f;
#pragma unroll
    for (int i = 0; i < kPartials / 4 / 256; ++i) {  // 2 float4 per thread
        float4 v = p4[tid + i * 256];
        sum += (v.x + v.y) + (v.z + v.w);
    }
#pragma unroll
    for (int off = 32; off > 0; off >>= 1) sum += __shfl_down(sum, off, 64);
    __shared__ float wsum[4];
    if ((tid & 63) == 0) wsum[tid >> 6] = sum;
    __syncthreads();
    if (tid == 0) out[0] = (wsum[0] + wsum[1] + wsum[2] + wsum[3]) * kScale;
}

extern "C" void kernel_launch(void* const* d_in, const int* in_sizes, int n_in,
                              void* d_out, int out_size, void* d_ws, size_t ws_size,
                              hipStream_t stream) {
    const float* xs = (const float*)d_in[0];
    const float* hx = (const float*)d_in[1];
    float* out = (float*)d_out;
    float* partials = (float*)d_ws;  // 2048 floats; every slot written each launch
    gyro_loss_kernel<<<kBlocks, kThreadsPerBlock, 0, stream>>>(xs, hx, partials);
    reduce_kernel<<<1, 256, 0, stream>>>(partials, out);
}

// Round 8
// 88.602 us; speedup vs baseline: 1.0239x; 1.0239x over previous
//
#include <hip/hip_runtime.h>
#include <math.h>

// GyroLoss: fused so3_exp / bmtm / so3_log / Huber-mean over (64, 8192) rows.
// R8: R5 structure (best: 88.5 us) with ONE change — per-wave LDS staging,
// no __syncthreads. Each wave stages exactly the 144 (xs) + 240 (hx) float4
// its own lanes consume; same-wave ds_write->ds_read ordering is handled by
// compiler-inserted lgkmcnt waits (same LDS array -> alias-tracked). This
// removes the all-waves vmcnt(0)+lgkmcnt(0) barrier drain.
// R7 lesson: 512-block no-LDS variant regressed (2 waves/SIMD too few for
// latency hiding) — 2048 blocks + LDS locality wins.

namespace {
constexpr int kN = 64;
constexpr int kT = 8192;
constexpr int kN0 = 5;
constexpr int kRows = kN * kT;                  // 524288
constexpr int kRowsPerBlock = 256;              // == blockDim.x
constexpr int kBlocks = kRows / kRowsPerBlock;  // 2048
constexpr int kWavesPerBlock = kRowsPerBlock / 64;   // 4
constexpr int kPartials = kBlocks * kWavesPerBlock;  // 8192
constexpr int kXs4PerWave = 64 * 9 / 4;   // 144 float4 staged per wave
constexpr int kHx4PerWave = 64 * 15 / 4;  // 240 float4 staged per wave
// out = W * HUBER^2 * mean = 25 * sum / (64 * 8187 * 15)
constexpr float kScale = (float)(25.0 / ((double)kN * (double)(kT - kN0) * 15.0));
}

// Abramowitz-Stegun 4.4.45: acos(x) ~ sqrt(1-|x|)*poly(|x|). Abs err ~1e-4 rad.
__device__ __forceinline__ float fast_acos(float x) {
    float xa = fabsf(x);
    float p = fmaf(xa, fmaf(xa, fmaf(xa, -0.0187293f, 0.0742610f), -0.2121144f), 1.5707288f);
    float r = sqrtf(fmaxf(1.0f - xa, 0.0f)) * p;
    return x < 0.0f ? 3.14159265f - r : r;
}

// Rodrigues: R = I + A*K + B*K^2. 1/theta via rsqrt — no divides, no sqrt.
__device__ __forceinline__ void so3_exp9(float x, float y, float z, float R[9]) {
    float t2 = x * x + y * y + z * z;
    bool sm = t2 < 1e-8f;
    float st2 = sm ? 1.0f : t2;
    float rth = rsqrtf(st2);       // 1/theta
    float th = st2 * rth;          // theta
    float s, c;
    __sincosf(th, &s, &c);
    float A = sm ? (1.0f - t2 * (1.0f / 6.0f)) : (s * rth);
    float B = sm ? (0.5f - t2 * (1.0f / 24.0f)) : ((1.0f - c) * rth * rth);
    R[0] = 1.0f - B * (y * y + z * z);
    R[1] = B * x * y - A * z;
    R[2] = B * x * z + A * y;
    R[3] = B * x * y + A * z;
    R[4] = 1.0f - B * (x * x + z * z);
    R[5] = B * y * z - A * x;
    R[6] = B * x * z - A * y;
    R[7] = B * y * z + A * x;
    R[8] = 1.0f - B * (x * x + y * y);
}

// out = so3_log(a^T * b); C[i][k] = sum_j a[3j+i] * b[3j+k]
__device__ __forceinline__ void bmtm_log(const float a[9], const float b[9], float out[3]) {
    float C00 = a[0] * b[0] + a[3] * b[3] + a[6] * b[6];
    float C11 = a[1] * b[1] + a[4] * b[4] + a[7] * b[7];
    float C22 = a[2] * b[2] + a[5] * b[5] + a[8] * b[8];
    float C21 = a[2] * b[1] + a[5] * b[4] + a[8] * b[7];
    float C12 = a[1] * b[2] + a[4] * b[5] + a[7] * b[8];
    float C02 = a[0] * b[2] + a[3] * b[5] + a[6] * b[8];
    float C20 = a[2] * b[0] + a[5] * b[3] + a[8] * b[6];
    float C10 = a[1] * b[0] + a[4] * b[3] + a[7] * b[6];
    float C01 = a[0] * b[1] + a[3] * b[4] + a[6] * b[7];
    float tr = C00 + C11 + C22;
    float cs = 0.5f * (tr - 1.0f);
    cs = fminf(1.0f, fmaxf(-1.0f, cs));
    bool sm = cs > (1.0f - 1e-6f);
    float ang = fast_acos(sm ? 0.0f : cs);
    // sin(acos(c)) == sqrt(1-c^2)
    float factor = sm ? 0.5f : 0.5f * ang * rsqrtf(fmaxf(1.0f - cs * cs, 1e-30f));
    out[0] = factor * (C21 - C12);
    out[1] = factor * (C02 - C20);
    out[2] = factor * (C10 - C01);
}

__device__ __forceinline__ float huber_term(float r) {
    float z = r * 200.0f;  // 1/HUBER
    float az = fabsf(z);
    return az < 1.0f ? 0.5f * z * z : az - 0.5f;
}

__global__ __launch_bounds__(256) void gyro_loss_kernel(
    const float* __restrict__ xs, const float* __restrict__ hx,
    float* __restrict__ partials) {
    __shared__ __align__(16) float s_xs[kRowsPerBlock * 9];   // 9216 B
    __shared__ __align__(16) float s_hx[kRowsPerBlock * 15];  // 15360 B
    const int tid = threadIdx.x;
    const int lane = tid & 63;
    const int w = tid >> 6;
    const long base_row = (long)blockIdx.x * kRowsPerBlock;

    // Per-wave staging: wave w stages ONLY the float4 range its lanes read.
    // No __syncthreads — same-wave ds_write->ds_read is lgkmcnt-ordered.
    const float4* gx4 = reinterpret_cast<const float4*>(xs + base_row * 9);
    const float4* gh4 = reinterpret_cast<const float4*>(hx + base_row * 15);
    float4* sx4 = reinterpret_cast<float4*>(s_xs);
    float4* sh4 = reinterpret_cast<float4*>(s_hx);
#pragma unroll
    for (int k = 0; k < 3; ++k) {  // 144 = 2*64 + 16
        int i = w * kXs4PerWave + lane + k * 64;
        if (k < 2 || lane < kXs4PerWave - 128) sx4[i] = gx4[i];
    }
#pragma unroll
    for (int k = 0; k < 4; ++k) {  // 240 = 3*64 + 48
        int i = w * kHx4PerWave + lane + k * 64;
        if (k < 3 || lane < kHx4PerWave - 192) sh4[i] = gh4[i];
    }

    const int row = (int)base_row + tid;
    const int t = row & (kT - 1);
    float sum = 0.0f;
    if (t >= kN0) {
        const float* x = s_xs + tid * 9;   // odd stride: conflict-free
        const float* h = s_hx + tid * 15;  // odd stride: conflict-free
        float Rw[9], Ro[9], Rx[9];
        so3_exp9(x[0], x[1], x[2], Rw);
        so3_exp9(h[0], h[1], h[2], Ro);
        so3_exp9(h[6], h[7], h[8], Rx);
        float l1[3], l3[3];
        bmtm_log(Rw, Ro, l1);
        bmtm_log(Rw, Rx, l3);
        sum += huber_term(6.0f * l1[0]) + huber_term(6.0f * l1[1]) + huber_term(6.0f * l1[2]);
        sum += huber_term(6.0f * (x[3] - h[3])) + huber_term(6.0f * (x[4] - h[4])) +
               huber_term(6.0f * (x[5] - h[5]));
        sum += huber_term(l3[0]) + huber_term(l3[1]) + huber_term(l3[2]);
        sum += huber_term(x[3] - h[9]) + huber_term(x[4] - h[10]) + huber_term(x[5] - h[11]);
        sum += huber_term(x[6] - h[12]) + huber_term(x[7] - h[13]) + huber_term(x[8] - h[14]);
    }

    // wave64 butterfly reduce; one plain store per wave. No barriers anywhere.
#pragma unroll
    for (int off = 32; off > 0; off >>= 1) sum += __shfl_down(sum, off, 64);
    if (lane == 0) partials[blockIdx.x * kWavesPerBlock + w] = sum;
}

__global__ __launch_bounds__(256) void reduce_kernel(const float* __restrict__ partials,
                                                     float* __restrict__ out) {
    const int tid = threadIdx.x;
    const float4* p4 = reinterpret_cast<const float4*>(partials);
    float sum = 0.0f;
#pragma unroll
    for (int i = 0; i < kPartials / 4 / 256; ++i) {  // 8 float4 per thread
        float4 v = p4[tid + i * 256];
        sum += (v.x + v.y) + (v.z + v.w);
    }
#pragma unroll
    for (int off = 32; off > 0; off >>= 1) sum += __shfl_down(sum, off, 64);
    __shared__ float wsum[4];
    if ((tid & 63) == 0) wsum[tid >> 6] = sum;
    __syncthreads();
    if (tid == 0) out[0] = (wsum[0] + wsum[1] + wsum[2] + wsum[3]) * kScale;
}

extern "C" void kernel_launch(void* const* d_in, const int* in_sizes, int n_in,
                              void* d_out, int out_size, void* d_ws, size_t ws_size,
                              hipStream_t stream) {
    const float* xs = (const float*)d_in[0];
    const float* hx = (const float*)d_in[1];
    float* out = (float*)d_out;
    float* partials = (float*)d_ws;  // 8192 floats; every slot written each launch
    gyro_loss_kernel<<<kBlocks, kRowsPerBlock, 0, stream>>>(xs, hx, partials);
    reduce_kernel<<<1, 256, 0, stream>>>(partials, out);
}